// Round 3
// baseline (71.591 us; speedup 1.0000x reference)
//
#include <hip/hip_runtime.h>

#define CF 2048
#define TT 64
#define TP 65
#define KK 16
#define SS 4
#define EE 64
#define BB 2
#define DT_CONST 0.005f
#define PART_STRIDE 20   // 17 slots used per block, padded

// ---------------- kernel A: distributed windowed-Gram partials ----------------
// grid 512 = b(2) * cfg(32) * oct(8); block 256 = 4 waves; lane = cf row in group.
// wave handles pairs p with (p & 31) == oct*4 + w  (4 or 5 pairs).
__global__ void __launch_bounds__(256) kA_gram(const float* __restrict__ events,
                                               float* __restrict__ ws) {
    int bid = blockIdx.x;
    int b   = bid >> 8;
    int cfg = (bid >> 3) & 31;
    int oct = bid & 7;
    int lane = threadIdx.x & 63;
    int w    = threadIdx.x >> 6;
    int gw   = oct * 4 + w;
    int cf = cfg * 64 + lane;
    const float* xp = events + (size_t)(b * CF + cf) * TT;
    float x[TT];
#pragma unroll
    for (int i = 0; i < TT / 4; ++i) {
        float4 v = reinterpret_cast<const float4*>(xp)[i];
        x[4*i] = v.x; x[4*i+1] = v.y; x[4*i+2] = v.z; x[4*i+3] = v.w;
    }
    float tot = 0.f;
#pragma unroll
    for (int u = 0; u < TT; ++u) tot += x[u];
    float S1[KK];
#pragma unroll
    for (int d = 0; d < KK; ++d) {
        float v = tot;
        if (d <= 7) {
#pragma unroll
            for (int u = d + 57; u < 64; ++u) v -= x[u];
        } else {
#pragma unroll
            for (int u = 0; u <= d - 9; ++u) v -= x[u];
        }
        S1[d] = v;
    }
    int p = 0;
#pragma unroll
    for (int d1 = 0; d1 < KK; ++d1) {
#pragma unroll
        for (int d2 = d1; d2 < KK; ++d2) {
            if ((p & 31) == gw) {         // wave-uniform
                const int lag = d2 - d1;
                const int lo = (d1 - 8 > 0) ? d1 - 8 : 0;
                const int hi = ((63 - lag) < (d1 + 56)) ? (63 - lag) : (d1 + 56);
                float g = 0.f;
#pragma unroll
                for (int u = lo; u <= hi; ++u) g += x[u] * x[u + lag];
                g -= S1[d1] * S1[d2] * (1.f / 65.f);
#pragma unroll
                for (int sft = 1; sft < 64; sft <<= 1) g += __shfl_xor(g, sft, 64);
                if (lane == 0)
                    ws[(size_t)bid * PART_STRIDE + w * 5 + (p >> 5)] = g;
            }
            ++p;
        }
    }
}

// ---------------- kernel B: redundant prologue + conv with coalesced writes ----
// grid 1024, block 256. Each block: reduce Gram partials -> Gfull (LDS),
// combined kernels, quadratic-form fv, MLP, wk (LDS); then 2 chunks of 128
// output rows staged through LDS.
__global__ void __launch_bounds__(256, 4) kB_main(
        const float* __restrict__ events, const float* __restrict__ tc,
        const float* __restrict__ tk, const float* __restrict__ w1,
        const float* __restrict__ b1, const float* __restrict__ w2,
        const float* __restrict__ b2, const float* __restrict__ ws,
        float* __restrict__ out) {
    __shared__ float buf[128 * TP];       // 8320 floats; prologue overlays below
    __shared__ float wkL[BB * EE * KK];   // 2048 floats, survives whole kernel
    float* Gf    = buf;                   // [2][16][16] = 512
    float* combL = buf + 512;             // [4][64][16] = 4096
    float* fvL   = buf + 4608;            // [2][4]
    int tid = threadIdx.x;

    // --- Gram partial reduce -> full symmetric G per b ---
    for (int V = tid; V < BB * 136; V += 256) {
        int b = V / 136, p = V % 136;
        int pp = p, d1 = 0;
        while (pp >= KK - d1) { pp -= KK - d1; ++d1; }
        int d2 = d1 + pp;
        int oct = (p & 31) >> 2, wv = p & 3, slot = p >> 5;
        float acc = 0.f;
#pragma unroll
        for (int cfg = 0; cfg < 32; ++cfg)
            acc += ws[(size_t)(b * 256 + cfg * 8 + oct) * PART_STRIDE + wv * 5 + slot];
        Gf[(b * KK + d1) * KK + d2] = acc;
        Gf[(b * KK + d2) * KK + d1] = acc;
    }
    // --- combined kernels: thread = (s,e) ---
    {
        int s = tid >> 6;
        float inv = DT_CONST / tc[s];
        float dk[KK]; float dsum = 0.f;
#pragma unroll
        for (int j = 0; j < KK; ++j) { dk[j] = expf(-(float)j * inv); dsum += dk[j]; }
        float rn = 1.f / dsum;
#pragma unroll
        for (int i = 0; i < KK / 4; ++i) {
            float4 v = reinterpret_cast<const float4*>(tk + tid * KK)[i];
            combL[tid * KK + 4*i + 0] = dk[4*i + 0] * rn * v.x;
            combL[tid * KK + 4*i + 1] = dk[4*i + 1] * rn * v.y;
            combL[tid * KK + 4*i + 2] = dk[4*i + 2] * rn * v.z;
            combL[tid * KK + 4*i + 3] = dk[4*i + 3] * rn * v.w;
        }
    }
    __syncthreads();
    // --- quadratic forms + e-reduction -> fv[b][s] ---
    {
        float c[KK];
#pragma unroll
        for (int i = 0; i < KK / 4; ++i) {
            float4 v = reinterpret_cast<const float4*>(combL + tid * KK)[i];
            c[4*i] = v.x; c[4*i+1] = v.y; c[4*i+2] = v.z; c[4*i+3] = v.w;
        }
        float acc0 = 0.f, acc1 = 0.f;
#pragma unroll
        for (int d1 = 0; d1 < KK; ++d1) {
            float cd1 = c[d1];
            float t0 = 0.5f * Gf[d1 * KK + d1] * cd1;
            float t1 = 0.5f * Gf[256 + d1 * KK + d1] * cd1;
#pragma unroll
            for (int d2 = d1 + 1; d2 < KK; ++d2) {
                t0 += Gf[d1 * KK + d2] * c[d2];
                t1 += Gf[256 + d1 * KK + d2] * c[d2];
            }
            acc0 += 2.f * cd1 * t0;
            acc1 += 2.f * cd1 * t1;
        }
#pragma unroll
        for (int sft = 1; sft < 64; sft <<= 1) {
            acc0 += __shfl_xor(acc0, sft, 64);
            acc1 += __shfl_xor(acc1, sft, 64);
        }
        __syncthreads();  // Gf reads done before fv overlays nothing; keep order safe
        if ((tid & 63) == 0) {
            int s = tid >> 6;
            const float scale = 1.f / 8388608.f;   // 1/(E * (Tp-1) * Cf)
            fvL[s]     = acc0 * scale;
            fvL[4 + s] = acc1 * scale;
        }
    }
    __syncthreads();
    // --- MLP + softmax (redundant per thread, only its own b) + wk ---
    {
        int bt = tid >> 7;
        float fv[SS];
#pragma unroll
        for (int s = 0; s < SS; ++s) fv[s] = fvL[bt * SS + s];
        float h[8];
#pragma unroll
        for (int i = 0; i < 8; ++i) {
            float a = b1[i];
#pragma unroll
            for (int s = 0; s < SS; ++s) a += fv[s] * w1[i * SS + s];
            h[i] = a > 0.f ? a : 0.f;
        }
        float lg[SS]; float mx = -1e30f;
#pragma unroll
        for (int s = 0; s < SS; ++s) {
            float a = b2[s];
#pragma unroll
            for (int i = 0; i < 8; ++i) a += h[i] * w2[s * 8 + i];
            lg[s] = a; mx = fmaxf(mx, a);
        }
        float se = 0.f;
#pragma unroll
        for (int s = 0; s < SS; ++s) { lg[s] = expf(lg[s] - mx); se += lg[s]; }
        float attn[SS];
#pragma unroll
        for (int s = 0; s < SS; ++s) attn[s] = lg[s] / se;
#pragma unroll
        for (int k = 0; k < 8; ++k) {
            int o = tid * 8 + k;
            int e = (o >> 4) & 63, dt = o & 15;
            float a = 0.f;
#pragma unroll
            for (int s = 0; s < SS; ++s)
                a += attn[s] * combL[(s * EE + e) * KK + dt];
            wkL[o] = a;
        }
    }
    __syncthreads();   // wk ready; buf free for conv staging

    // --- conv: 2 chunks of 128 rows, 2 threads per row (t-halves) ---
    int r = tid & 127;
    int hh = tid >> 7;                    // 0: t in [0,32], 1: t in [33,64]
#pragma unroll 1
    for (int it = 0; it < 2; ++it) {
        int c = blockIdx.x + it * 1024;   // chunk id, < 2048
        int be = c >> 4;
        int b  = c >> 10;
        float wkr[KK];
#pragma unroll
        for (int i = 0; i < KK / 4; ++i) {
            float4 v = reinterpret_cast<const float4*>(wkL + be * KK)[i];
            wkr[4*i] = v.x; wkr[4*i+1] = v.y; wkr[4*i+2] = v.z; wkr[4*i+3] = v.w;
        }
        int cfrow = (c * 128 + r) & (CF - 1);
        const float* xr = events + (size_t)(b * CF + cfrow) * TT;
        float wnd[48];
        float* bp = buf + r * TP;
        if (hh == 0) {
#pragma unroll
            for (int k = 0; k < 8; ++k) wnd[k] = 0.f;
#pragma unroll
            for (int k = 0; k < 10; ++k) {
                float4 v = reinterpret_cast<const float4*>(xr)[k];
                wnd[8+4*k] = v.x; wnd[9+4*k] = v.y; wnd[10+4*k] = v.z; wnd[11+4*k] = v.w;
            }
#pragma unroll
            for (int i = 0; i <= 32; ++i) {
                float a = 0.f;
#pragma unroll
                for (int dt = 0; dt < KK; ++dt) a += wkr[dt] * wnd[i + dt];
                bp[i] = a;
            }
        } else {
#pragma unroll
            for (int k = 0; k < 10; ++k) {
                float4 v = reinterpret_cast<const float4*>(xr + 24)[k];
                wnd[4*k] = v.x; wnd[1+4*k] = v.y; wnd[2+4*k] = v.z; wnd[3+4*k] = v.w;
            }
#pragma unroll
            for (int k = 40; k < 48; ++k) wnd[k] = 0.f;
#pragma unroll
            for (int i = 0; i < 32; ++i) {
                float a = 0.f;
#pragma unroll
                for (int dt = 0; dt < KK; ++dt) a += wkr[dt] * wnd[1 + i + dt];
                bp[33 + i] = a;
            }
        }
        __syncthreads();
        const float4* bs = reinterpret_cast<const float4*>(buf);
        float4* od = reinterpret_cast<float4*>(out + (size_t)c * (128 * TP));
        for (int j = tid; j < 128 * TP / 4; j += 256)
            od[j] = bs[j];
        __syncthreads();
    }
}

extern "C" void kernel_launch(void* const* d_in, const int* in_sizes, int n_in,
                              void* d_out, int out_size, void* d_ws, size_t ws_size,
                              hipStream_t stream) {
    const float* events = (const float*)d_in[0];
    const float* tc     = (const float*)d_in[1];
    const float* tk     = (const float*)d_in[2];
    const float* w1     = (const float*)d_in[3];
    const float* b1     = (const float*)d_in[4];
    const float* w2     = (const float*)d_in[5];
    const float* b2     = (const float*)d_in[6];
    float* out = (float*)d_out;
    float* ws  = (float*)d_ws;

    hipLaunchKernelGGL(kA_gram, dim3(512),  dim3(256), 0, stream, events, ws);
    hipLaunchKernelGGL(kB_main, dim3(1024), dim3(256), 0, stream,
                       events, tc, tk, w1, b1, w2, b2, ws, out);
}

// Round 4
// 55.451 us; speedup vs baseline: 1.2911x; 1.2911x over previous
//
#include <hip/hip_runtime.h>

#define CF 2048
#define TT 64
#define TP 65
#define KK 16
#define SS 4
#define EE 64
#define BB 2
#define DT_CONST 0.005f

// ws layout (floats)
#define PART_OFF 0        // gram partials [64 blocks][136]
#define WK_OFF   8704     // wk [2][64][16] = 2048

// ---------------- kernel A: windowed Gram, scratch-free ----------------
// grid 64; block 256 = 4 waves; wave = 16 rows; lane = 4*row_local + chunk.
// Per row: A[lag] full autocorr (4 chunks of 16), head/tail corrections.
__global__ void __launch_bounds__(256, 1) kA_gram(const float* __restrict__ events,
                                                  float* __restrict__ ws) {
    __shared__ float part[4][136];
    const int tid  = threadIdx.x;
    const int wv   = tid >> 6;
    const int l    = tid & 63;
    const int rl   = l >> 2;
    const int ch   = l & 3;
    const int rowg = blockIdx.x * 64 + wv * 16 + rl;   // [0,4096) = (b,cf)
    const float* xp = events + (size_t)rowg * TT;

    float win[32];
    if (ch < 3) {
#pragma unroll
        for (int k = 0; k < 8; ++k) {
            float4 v = reinterpret_cast<const float4*>(xp + 16 * ch)[k];
            win[4*k] = v.x; win[4*k+1] = v.y; win[4*k+2] = v.z; win[4*k+3] = v.w;
        }
    } else {
#pragma unroll
        for (int k = 0; k < 4; ++k) {
            float4 v = reinterpret_cast<const float4*>(xp + 48)[k];
            win[4*k] = v.x; win[4*k+1] = v.y; win[4*k+2] = v.z; win[4*k+3] = v.w;
        }
#pragma unroll
        for (int k = 16; k < 32; ++k) win[k] = 0.f;
    }

    float csum = 0.f;
#pragma unroll
    for (int i = 0; i < 16; ++i) csum += win[i];
    float tot = csum;
    tot += __shfl_xor(tot, 1, 64);
    tot += __shfl_xor(tot, 2, 64);

    // full-range autocorr partials; ch3 zeros give natural truncation
    float A[16];
#pragma unroll
    for (int lag = 0; lag < 16; ++lag) {
        float a = 0.f;
#pragma unroll
        for (int i = 0; i < 16; ++i) a += win[i] * win[i + lag];
        a += __shfl_xor(a, 1, 64);
        a += __shfl_xor(a, 2, 64);
        A[lag] = a;
    }

    // head prefix sums (valid on ch==0): hs[k] = sum_{v=0..k} x[v]
    float hs[7];
    hs[0] = win[0];
#pragma unroll
    for (int k = 1; k < 7; ++k) hs[k] = hs[k-1] + win[k];
    // tail suffix sums (valid on ch==3): ts[j] = sum_{v=57+j..63} x[v]
    float ts[7];
    ts[6] = win[15];
#pragma unroll
    for (int j = 5; j >= 0; --j) ts[j] = ts[j+1] + win[9 + j];

    // H (ch0): for d1>=9: sum_{v=0}^{d1-9} x[v]x[v+lag]
    float H[28];
    {
        int hi2 = 0;
#pragma unroll
        for (int d1 = 9; d1 < 16; ++d1)
#pragma unroll
            for (int lag = 0; lag <= 15 - d1; ++lag) {
                float s = 0.f;
#pragma unroll
                for (int v = 0; v <= d1 - 9; ++v) s += win[v] * win[v + lag];
                H[hi2++] = s;
            }
    }
    // T (ch3): for d2<=6: sum_{i=d1+9}^{15-lag} win[i]win[i+lag]
    float T[28];
    {
        int ti2 = 0;
#pragma unroll
        for (int d1 = 0; d1 <= 6; ++d1)
#pragma unroll
            for (int d2 = d1; d2 <= 6; ++d2) {
                const int lag = d2 - d1;
                float s = 0.f;
#pragma unroll
                for (int i = d1 + 9; i <= 15 - lag; ++i) s += win[i] * win[i + lag];
                T[ti2++] = s;
            }
    }
    // broadcast ch3 data to the quad
    const int src3 = l | 3;
    float Tb[28], tsb[7];
#pragma unroll
    for (int k = 0; k < 28; ++k) Tb[k] = __shfl(T[k], src3, 64);
#pragma unroll
    for (int k = 0; k < 7; ++k) tsb[k] = __shfl(ts[k], src3, 64);

    float S1[16];
#pragma unroll
    for (int d = 0; d < 16; ++d)
        S1[d] = (d <= 6) ? (tot - tsb[d]) : ((d <= 8) ? tot : (tot - hs[d - 9]));

    // assemble pairs (valid on ch==0 lanes), reduce over 16 rows, store
    {
        int hI = 0, tI = 0, p = 0;
#pragma unroll
        for (int d1 = 0; d1 < 16; ++d1)
#pragma unroll
            for (int d2 = d1; d2 < 16; ++d2) {
                const int lag = d2 - d1;
                float g = A[lag] - S1[d1] * S1[d2] * (1.f / 65.f);
                if (d1 >= 9) { g -= H[hI]; ++hI; }
                if (d2 <= 6) { g -= Tb[tI]; ++tI; }
                g += __shfl_xor(g, 4, 64);
                g += __shfl_xor(g, 8, 64);
                g += __shfl_xor(g, 16, 64);
                g += __shfl_xor(g, 32, 64);
                if (l == 0) part[wv][p] = g;
                ++p;
            }
    }
    __syncthreads();
    if (tid < 136)
        ws[PART_OFF + blockIdx.x * 136 + tid] =
            part[0][tid] + part[1][tid] + part[2][tid] + part[3][tid];
}

// ---------------- kernel M: reduce partials, fv, MLP, softmax, wk ----------------
__global__ void __launch_bounds__(256, 1) kM_mlp(const float* __restrict__ tc,
        const float* __restrict__ tk, const float* __restrict__ w1,
        const float* __restrict__ b1, const float* __restrict__ w2,
        const float* __restrict__ b2, float* __restrict__ ws) {
    __shared__ float Gf[BB][KK][KK];
    __shared__ float combL[SS * EE * KK];
    __shared__ float fvL[BB * SS];
    const int tid = threadIdx.x;
    for (int V = tid; V < BB * 136; V += 256) {
        int b = V / 136, p = V % 136;
        int pp = p, d1 = 0;
        while (pp >= KK - d1) { pp -= KK - d1; ++d1; }
        int d2 = d1 + pp;
        float acc = 0.f;
        for (int blk = 0; blk < 32; ++blk)
            acc += ws[PART_OFF + (size_t)(b * 32 + blk) * 136 + p];
        Gf[b][d1][d2] = acc;
        Gf[b][d2][d1] = acc;
    }
    {
        int s = tid >> 6;
        float inv = DT_CONST / tc[s];
        float dk[KK]; float dsum = 0.f;
#pragma unroll
        for (int j = 0; j < KK; ++j) { dk[j] = expf(-(float)j * inv); dsum += dk[j]; }
        float rn = 1.f / dsum;
#pragma unroll
        for (int i = 0; i < 4; ++i) {
            float4 v = reinterpret_cast<const float4*>(tk + tid * KK)[i];
            combL[tid * KK + 4*i + 0] = dk[4*i + 0] * rn * v.x;
            combL[tid * KK + 4*i + 1] = dk[4*i + 1] * rn * v.y;
            combL[tid * KK + 4*i + 2] = dk[4*i + 2] * rn * v.z;
            combL[tid * KK + 4*i + 3] = dk[4*i + 3] * rn * v.w;
        }
    }
    __syncthreads();
    {
        float c[KK];
#pragma unroll
        for (int i = 0; i < 4; ++i) {
            float4 v = reinterpret_cast<const float4*>(combL + tid * KK)[i];
            c[4*i] = v.x; c[4*i+1] = v.y; c[4*i+2] = v.z; c[4*i+3] = v.w;
        }
        float acc0 = 0.f, acc1 = 0.f;
#pragma unroll
        for (int d1 = 0; d1 < KK; ++d1) {
            float cd1 = c[d1];
            float t0 = 0.5f * Gf[0][d1][d1] * cd1;
            float t1 = 0.5f * Gf[1][d1][d1] * cd1;
#pragma unroll
            for (int d2 = d1 + 1; d2 < KK; ++d2) {
                t0 += Gf[0][d1][d2] * c[d2];
                t1 += Gf[1][d1][d2] * c[d2];
            }
            acc0 += 2.f * cd1 * t0;
            acc1 += 2.f * cd1 * t1;
        }
#pragma unroll
        for (int sft = 1; sft < 64; sft <<= 1) {
            acc0 += __shfl_xor(acc0, sft, 64);
            acc1 += __shfl_xor(acc1, sft, 64);
        }
        if ((tid & 63) == 0) {
            const float scale = 1.f / 8388608.f;   // 1/(E*(Tp-1)*Cf)
            fvL[(tid >> 6)]     = acc0 * scale;
            fvL[4 + (tid >> 6)] = acc1 * scale;
        }
    }
    __syncthreads();
    {
        int bt = tid >> 7;
        float fv[SS];
#pragma unroll
        for (int s = 0; s < SS; ++s) fv[s] = fvL[bt * SS + s];
        float h[8];
#pragma unroll
        for (int i = 0; i < 8; ++i) {
            float a = b1[i];
#pragma unroll
            for (int s = 0; s < SS; ++s) a += fv[s] * w1[i * SS + s];
            h[i] = a > 0.f ? a : 0.f;
        }
        float lg[SS]; float mx = -1e30f;
#pragma unroll
        for (int s = 0; s < SS; ++s) {
            float a = b2[s];
#pragma unroll
            for (int i = 0; i < 8; ++i) a += h[i] * w2[s * 8 + i];
            lg[s] = a; mx = fmaxf(mx, a);
        }
        float se = 0.f;
#pragma unroll
        for (int s = 0; s < SS; ++s) { lg[s] = expf(lg[s] - mx); se += lg[s]; }
        float attn[SS];
#pragma unroll
        for (int s = 0; s < SS; ++s) attn[s] = lg[s] / se;
#pragma unroll
        for (int k = 0; k < 8; ++k) {
            int o = tid * 8 + k;                 // o>>10 == bt for all k
            int e = (o >> 4) & 63, dt2 = o & 15;
            float a = 0.f;
#pragma unroll
            for (int s = 0; s < SS; ++s)
                a += attn[s] * combL[(s * EE + e) * KK + dt2];
            ws[WK_OFF + o] = a;
        }
    }
}

// ---------------- kernel C: conv, seg-chunked (no scratch), coalesced writes ----
// grid 4096 chunks of 64 rows; block 256 = 4 waves; wave=seg(16 t's), lane=row.
__global__ void __launch_bounds__(256, 4) kC_conv(const float* __restrict__ events,
                                                  const float* __restrict__ ws,
                                                  float* __restrict__ out) {
    __shared__ float buf[64 * TP];               // 16640 B
    const int tid = threadIdx.x;
    const int seg = tid >> 6;                    // wave-uniform
    const int r   = tid & 63;
    const int c   = blockIdx.x;                  // [0,4096)
    const int be  = c >> 5;
    const int rowg = (c << 6) + r;               // [0, 262144)
    const int b   = be >> 6;
    const float* xr = events + (((size_t)b << 11) + (rowg & (CF - 1))) * TT;

    float wk[KK];
#pragma unroll
    for (int i = 0; i < 4; ++i) {
        float4 v = reinterpret_cast<const float4*>(ws + WK_OFF + be * KK)[i];
        wk[4*i] = v.x; wk[4*i+1] = v.y; wk[4*i+2] = v.z; wk[4*i+3] = v.w;
    }

    float win[32];
    if (seg == 0) {                              // t 0..15, u -8..22
#pragma unroll
        for (int k = 0; k < 8; ++k) win[k] = 0.f;
#pragma unroll
        for (int k = 0; k < 6; ++k) {
            float4 v = reinterpret_cast<const float4*>(xr)[k];
            win[8+4*k] = v.x; win[9+4*k] = v.y; win[10+4*k] = v.z; win[11+4*k] = v.w;
        }
    } else if (seg == 3) {                       // t 48..64, u 40..71
#pragma unroll
        for (int k = 0; k < 6; ++k) {
            float4 v = reinterpret_cast<const float4*>(xr + 40)[k];
            win[4*k] = v.x; win[4*k+1] = v.y; win[4*k+2] = v.z; win[4*k+3] = v.w;
        }
#pragma unroll
        for (int k = 24; k < 32; ++k) win[k] = 0.f;
    } else {                                     // seg1: u 8..39, seg2: u 24..55
        const float* bp2 = xr + (seg == 1 ? 8 : 24);
#pragma unroll
        for (int k = 0; k < 8; ++k) {
            float4 v = reinterpret_cast<const float4*>(bp2)[k];
            win[4*k] = v.x; win[4*k+1] = v.y; win[4*k+2] = v.z; win[4*k+3] = v.w;
        }
    }

    float acc[16];
#pragma unroll
    for (int i = 0; i < 16; ++i) acc[i] = 0.f;
#pragma unroll
    for (int dt = 0; dt < 16; ++dt) {
        float w = wk[dt];
#pragma unroll
        for (int i = 0; i < 16; ++i) acc[i] += w * win[i + dt];
    }
    float acc16 = 0.f;
    if (seg == 3) {
#pragma unroll
        for (int dt = 0; dt < 8; ++dt) acc16 += wk[dt] * win[16 + dt];
    }

    float* bp = buf + r * TP + seg * 16;
#pragma unroll
    for (int i = 0; i < 16; ++i) bp[i] = acc[i];
    if (seg == 3) bp[16] = acc16;
    __syncthreads();

    const float4* bs = reinterpret_cast<const float4*>(buf);
    float4* od = reinterpret_cast<float4*>(out + (size_t)c * (64 * TP));
    for (int j = tid; j < 64 * TP / 4; j += 256)
        od[j] = bs[j];
}

extern "C" void kernel_launch(void* const* d_in, const int* in_sizes, int n_in,
                              void* d_out, int out_size, void* d_ws, size_t ws_size,
                              hipStream_t stream) {
    const float* events = (const float*)d_in[0];
    const float* tc     = (const float*)d_in[1];
    const float* tk     = (const float*)d_in[2];
    const float* w1     = (const float*)d_in[3];
    const float* b1     = (const float*)d_in[4];
    const float* w2     = (const float*)d_in[5];
    const float* b2     = (const float*)d_in[6];
    float* out = (float*)d_out;
    float* ws  = (float*)d_ws;

    hipLaunchKernelGGL(kA_gram, dim3(64),   dim3(256), 0, stream, events, ws);
    hipLaunchKernelGGL(kM_mlp,  dim3(1),    dim3(256), 0, stream, tc, tk, w1, b1, w2, b2, ws);
    hipLaunchKernelGGL(kC_conv, dim3(4096), dim3(256), 0, stream, events, ws, out);
}